// Round 10
// baseline (160.534 us; speedup 1.0000x reference)
//
#include <hip/hip_runtime.h>

typedef unsigned short u16;
typedef unsigned int u32;
typedef __attribute__((ext_vector_type(8))) short bf16x8;
typedef __attribute__((ext_vector_type(4))) float f32x4;
typedef __attribute__((ext_vector_type(4))) unsigned short u16x4;
typedef __attribute__((ext_vector_type(2))) unsigned int u32x2;

// B=2, T=2048, E=768, H=12, HD=64
#define GM 4096   // B*T
#define GN 768
#define GK 768
#define QSCALE 0.18033688011112042f   // 0.125 * log2(e), folded into Q

static __device__ __forceinline__ u16 f2bf(float f) {
  union { float f; unsigned u; } v; v.f = f;
  unsigned u = v.u;
  return (u16)((u + 0x7FFFu + ((u >> 16) & 1u)) >> 16);
}

static __device__ __forceinline__ float exp2_hw(float x) {
  float r;
  asm("v_exp_f32 %0, %1" : "=v"(r) : "v"(x));
  return r;
}

static __device__ __forceinline__ u32 pack_rn(float lo, float hi) {
  u32 a = __float_as_uint(lo) + 0x8000u;
  u32 b = __float_as_uint(hi) + 0x8000u;
  return (a >> 16) | (b & 0xFFFF0000u);
}

// volatile global 16B load: CANNOT be sunk by the scheduler (R8 lesson)
static __device__ __forceinline__ bf16x8 gl16(const u16* p) {
  bf16x8 r;
  asm volatile("global_load_dwordx4 %0, %1, off" : "=v"(r) : "v"(p));
  return r;
}

static __device__ __forceinline__ void gld16(const void* g, void* l) {
  __builtin_amdgcn_global_load_lds((__attribute__((address_space(1))) void*)(g),
                                   (__attribute__((address_space(3))) void*)(l),
                                   16, 0, 0);
}

// ---------------- fp32 -> bf16 converts ----------------
__global__ void cvt_bf16(const float* __restrict__ in, u16* __restrict__ out, int n4) {
  int i = blockIdx.x * blockDim.x + threadIdx.x;
  if (i < n4) {
    float4 v = ((const float4*)in)[i];
    u16x4 o;
    o[0] = f2bf(v.x); o[1] = f2bf(v.y); o[2] = f2bf(v.z); o[3] = f2bf(v.w);
    ((u16x4*)out)[i] = o;
  }
}

__global__ void cvt_w4(const float* __restrict__ w0, const float* __restrict__ w1,
                       const float* __restrict__ w2, const float* __restrict__ w3,
                       u16* __restrict__ o0, u16* __restrict__ o1,
                       u16* __restrict__ o2, u16* __restrict__ o3, int n4) {
  const float* in = blockIdx.y == 0 ? w0 : (blockIdx.y == 1 ? w1 : (blockIdx.y == 2 ? w2 : w3));
  u16* out = blockIdx.y == 0 ? o0 : (blockIdx.y == 1 ? o1 : (blockIdx.y == 2 ? o2 : o3));
  int i = blockIdx.x * blockDim.x + threadIdx.x;
  if (i < n4) {
    float4 v = ((const float4*)in)[i];
    u16x4 o;
    o[0] = f2bf(v.x); o[1] = f2bf(v.y); o[2] = f2bf(v.z); o[3] = f2bf(v.w);
    ((u16x4*)out)[i] = o;
  }
}

// ---------------- GEMM: C(MxN) = scale * A(MxK) * Bt(NxK)^T ----------------
template<int F32OUT>
static __device__ __forceinline__ void gemm_core(const u16* __restrict__ A,
                                                 const u16* __restrict__ B,
                                                 void* __restrict__ O,
                                                 u16* lA, u16* lB, float scale)
{
  const int tid = threadIdx.x;
  const int wave = tid >> 6, lane = tid & 63;
  const int g = lane >> 4, c = lane & 15;
  const int wr = (wave >> 1) * 64, wc = (wave & 1) * 64;
  const int tm = blockIdx.x * 128, tn = blockIdx.y * 128;

  f32x4 acc[4][4] = {};

  const int srow = lane >> 2;
  const int scolb = (lane & 3) * 16;
  const char* gA = (const char*)(A + (size_t)tm * GK);
  const char* gB = (const char*)(B + (size_t)tn * GK);

  for (int k0 = 0; k0 < GK; k0 += 32) {
#pragma unroll
    for (int i = 0; i < 2; ++i) {
      const int chunk = wave * 2 + i;
      const int row = chunk * 16 + srow;
      gld16(gA + (size_t)row * (GK * 2) + k0 * 2 + scolb, (char*)lA + chunk * 1024);
      gld16(gB + (size_t)row * (GK * 2) + k0 * 2 + scolb, (char*)lB + chunk * 1024);
    }
    __syncthreads();
    bf16x8 af[4], bfr[4];
#pragma unroll
    for (int m = 0; m < 4; ++m)
      af[m] = *(const bf16x8*)((const char*)lA + (wr + m * 16 + c) * 64 + g * 16);
#pragma unroll
    for (int n = 0; n < 4; ++n)
      bfr[n] = *(const bf16x8*)((const char*)lB + (wc + n * 16 + c) * 64 + g * 16);
#pragma unroll
    for (int m = 0; m < 4; ++m)
#pragma unroll
      for (int n = 0; n < 4; ++n)
        acc[m][n] = __builtin_amdgcn_mfma_f32_16x16x32_bf16(af[m], bfr[n], acc[m][n], 0, 0, 0);
    __syncthreads();
  }

#pragma unroll
  for (int m = 0; m < 4; ++m)
#pragma unroll
    for (int n = 0; n < 4; ++n) {
      const int row0 = tm + wr + m * 16 + g * 4;
      const int col = tn + wc + n * 16 + c;
#pragma unroll
      for (int r = 0; r < 4; ++r) {
        if (F32OUT)
          ((float*)O)[(size_t)(row0 + r) * GN + col] = acc[m][n][r];
        else
          ((u16*)O)[(size_t)(row0 + r) * GN + col] = f2bf(acc[m][n][r] * scale);
      }
    }
}

__global__ __launch_bounds__(256) void gemm_qkv(const u16* __restrict__ A,
    const u16* __restrict__ B0, const u16* __restrict__ B1, const u16* __restrict__ B2,
    u16* __restrict__ O0, u16* __restrict__ O1, u16* __restrict__ O2)
{
  __shared__ u16 lA[4096], lB[4096];
  const u16* B = blockIdx.z == 0 ? B0 : (blockIdx.z == 1 ? B1 : B2);
  u16* O = blockIdx.z == 0 ? O0 : (blockIdx.z == 1 ? O1 : O2);
  const float scale = blockIdx.z == 0 ? QSCALE : 1.0f;
  gemm_core<0>(A, B, O, lA, lB, scale);
}

__global__ __launch_bounds__(256) void gemm_pool(const u16* __restrict__ A,
    const u16* __restrict__ B, float* __restrict__ O)
{
  __shared__ u16 lA[4096], lB[4096];
  gemm_core<1>(A, B, O, lA, lB, 1.0f);
}

// ---------------- V transpose: per head (2048x64) -> (64x2048) ----------------
__global__ __launch_bounds__(256) void vtrans(const u16* __restrict__ V, u16* __restrict__ VT) {
  const int tblk = blockIdx.x;
  const int bh = blockIdx.y;
  __shared__ u16 tile[64][72];
  const u16* Vh = V + (size_t)bh * 131072;
  u16* Vt = VT + (size_t)bh * 131072;
  const int tid = threadIdx.x;
  const int t0 = tblk * 64;
#pragma unroll
  for (int i = 0; i < 4; ++i) {
    int idx = i * 256 + tid;
    int row = idx >> 4;
    int c4 = idx & 15;
    u16x4 v = *(const u16x4*)(Vh + (size_t)(t0 + row) * 64 + c4 * 4);
    tile[row][c4 * 4 + 0] = v[0]; tile[row][c4 * 4 + 1] = v[1];
    tile[row][c4 * 4 + 2] = v[2]; tile[row][c4 * 4 + 3] = v[3];
  }
  __syncthreads();
#pragma unroll
  for (int i = 0; i < 4; ++i) {
    int idx = i * 256 + tid;
    int d = idx >> 4;
    int t4 = idx & 15;
    u16x4 o;
    o[0] = tile[t4 * 4 + 0][d]; o[1] = tile[t4 * 4 + 1][d];
    o[2] = tile[t4 * 4 + 2][d]; o[3] = tile[t4 * 4 + 3][d];
    *(u16x4*)(Vt + (size_t)d * 2048 + t0 + t4 * 4) = o;
  }
}

// ---------------- flash attention: barrier-free, pinned occupancy ----------------
// waves_per_eu(4,4): VGPR budget exactly 128 (R9's allocator chose 64 chasing
// 8 waves/EU and spilled 14MB/dispatch). V issued AFTER the QK cluster to cut
// peak pressure; its L2 latency hides under exp/pack + cross-wave TLP.
// Per tile: wait K(kt) -> QK -> issue V(kt) -> issue K(kt+1) -> exp/pack ->
// wait vmcnt(8) [V done, K in flight] -> PV. Last tile peeled.
template<bool PRE>
static __device__ __forceinline__ void attn_tile(
    const u16* __restrict__ Kh, const u16* __restrict__ Vh,
    int kt, int q0, bf16x8 (&kf)[2][4], const bf16x8 (&qf)[2],
    f32x4 (&oacc)[4], float& lsum, u16* pl, int g, int c, int swz)
{
  // K(kt) (and any prior V) complete
  asm volatile("s_waitcnt vmcnt(0)" ::: "memory");
  __builtin_amdgcn_sched_barrier(0);
  // S^T = K Q^T (keys lane-local)
  f32x4 s[4] = {};
  __builtin_amdgcn_s_setprio(1);
#pragma unroll
  for (int kk = 0; kk < 2; ++kk)
#pragma unroll
    for (int n = 0; n < 4; ++n)
      s[n] = __builtin_amdgcn_mfma_f32_16x16x32_bf16(kf[kk][n], qf[kk], s[n], 0, 0, 0);
  __builtin_amdgcn_s_setprio(0);
  __builtin_amdgcn_sched_barrier(0);
  // issue V(kt) now (kf regs just consumed; peak pressure lower than pre-QK issue)
  bf16x8 vf[2][4];
#pragma unroll
  for (int kk = 0; kk < 2; ++kk)
#pragma unroll
    for (int n = 0; n < 4; ++n)
      vf[kk][n] = gl16(Vh + (size_t)(n * 16 + c) * 2048 + kt * 64 + kk * 32 + g * 8);
  // prefetch K(kt+1) into the same kf regs (QK already issued -> WAR safe)
  if (PRE) {
#pragma unroll
    for (int kk = 0; kk < 2; ++kk)
#pragma unroll
      for (int n = 0; n < 4; ++n)
        kf[kk][n] = gl16(Kh + (size_t)(kt * 64 + 64 + n * 16 + c) * 64 + kk * 32 + g * 8);
  }
  // p = 2^s (Q pre-scaled); pack to bf16; one b64 LDS write per n-frag
  if (!PRE) {   // last tile: causal mask
    const int qrow = q0 + c;
#pragma unroll
    for (int n = 0; n < 4; ++n) {
      const int k0i = kt * 64 + n * 16 + g * 4;
      float p0 = (k0i + 0 > qrow) ? 0.f : exp2_hw(s[n][0]);
      float p1 = (k0i + 1 > qrow) ? 0.f : exp2_hw(s[n][1]);
      float p2 = (k0i + 2 > qrow) ? 0.f : exp2_hw(s[n][2]);
      float p3 = (k0i + 3 > qrow) ? 0.f : exp2_hw(s[n][3]);
      lsum += (p0 + p1) + (p2 + p3);
      u32x2 pw; pw[0] = pack_rn(p0, p1); pw[1] = pack_rn(p2, p3);
      *(u32x2*)((char*)pl + c * 128 + ((n * 32 + g * 8) ^ swz)) = pw;
    }
  } else {
#pragma unroll
    for (int n = 0; n < 4; ++n) {
      float p0 = exp2_hw(s[n][0]);
      float p1 = exp2_hw(s[n][1]);
      float p2 = exp2_hw(s[n][2]);
      float p3 = exp2_hw(s[n][3]);
      lsum += (p0 + p1) + (p2 + p3);
      u32x2 pw; pw[0] = pack_rn(p0, p1); pw[1] = pack_rn(p2, p3);
      *(u32x2*)((char*)pl + c * 128 + ((n * 32 + g * 8) ^ swz)) = pw;
    }
  }
  // wait V (K(kt+1) stays in flight when PRE)
  if (PRE) asm volatile("s_waitcnt vmcnt(8)" ::: "memory");
  else     asm volatile("s_waitcnt vmcnt(0)" ::: "memory");
  __builtin_amdgcn_sched_barrier(0);
  // O += P V
  __builtin_amdgcn_s_setprio(1);
#pragma unroll
  for (int kk = 0; kk < 2; ++kk) {
    bf16x8 pa = *(const bf16x8*)((const char*)pl + c * 128 + ((kk * 64 + g * 16) ^ swz));
#pragma unroll
    for (int n = 0; n < 4; ++n)
      oacc[n] = __builtin_amdgcn_mfma_f32_16x16x32_bf16(pa, vf[kk][n], oacc[n], 0, 0, 0);
  }
  __builtin_amdgcn_s_setprio(0);
}

__global__ __launch_bounds__(256)
__attribute__((amdgpu_waves_per_eu(4, 4)))
void attn(const u16* __restrict__ Q,
          const u16* __restrict__ Km,
          const u16* __restrict__ VT,
          u16* __restrict__ X2)
{
  const int tid = threadIdx.x, wave = tid >> 6, lane = tid & 63;
  const int g = lane >> 4, c = lane & 15;
  const int swz = ((c & 7) ^ (c >> 3)) << 4;      // P tile swizzle (row = c)

  // XCD-local bh (3 per XCD) + complementary q16-units per block (flat 67.5 tiles)
  const int lin = blockIdx.x;
  const int xcd = lin & 7, j = lin >> 3;
  const int bh = 3 * xcd + (j >> 5);
  const int a  = j & 31;
  const int u  = (wave == 0) ? a : (wave == 1) ? 63 - a : (wave == 2) ? 64 + a : 127 - a;
  const int b = bh / 12, h = bh % 12;
  const int q0 = u * 16;
  const int nkt = (u >> 2) + 1;

  __shared__ u16 Plds[4][1024];
  u16* pl = Plds[wave];

  const u16* Kh = Km + (size_t)bh * 131072;
  const u16* Vh = VT + (size_t)bh * 131072;   // [64][2048]
  const u16* Qh = Q + (size_t)bh * 131072;

  // issue K(0)
  bf16x8 kf[2][4];
#pragma unroll
  for (int kk = 0; kk < 2; ++kk)
#pragma unroll
    for (int n = 0; n < 4; ++n)
      kf[kk][n] = gl16(Kh + (size_t)(n * 16 + c) * 64 + kk * 32 + g * 8);

  bf16x8 qf[2];
#pragma unroll
  for (int kk = 0; kk < 2; ++kk)
    qf[kk] = *(const bf16x8*)(Qh + (size_t)(q0 + c) * 64 + kk * 32 + g * 8);

  f32x4 oacc[4] = {};
  float lsum = 0.f;

  for (int kt = 0; kt < nkt - 1; ++kt)
    attn_tile<true>(Kh, Vh, kt, q0, kf, qf, oacc, lsum, pl, g, c, swz);
  attn_tile<false>(Kh, Vh, nkt - 1, q0, kf, qf, oacc, lsum, pl, g, c, swz);

  // epilogue: reduce lsum across the 4 lanes sharing qrow c, broadcast, normalize
  float tot = lsum;
  tot += __shfl_xor(tot, 16);
  tot += __shfl_xor(tot, 32);
  float linv[4];
#pragma unroll
  for (int r = 0; r < 4; ++r)
    linv[r] = __frcp_rn(__shfl(tot, g * 4 + r));
#pragma unroll
  for (int n = 0; n < 4; ++n)
#pragma unroll
    for (int r = 0; r < 4; ++r) {
      const float o = oacc[n][r] * linv[r];
      const int t = q0 + g * 4 + r;
      X2[((size_t)b * 2048 + t) * 768 + h * 64 + n * 16 + c] = f2bf(o);
    }
}

// ---------------- host ----------------
extern "C" void kernel_launch(void* const* d_in, const int* in_sizes, int n_in,
                              void* d_out, int out_size, void* d_ws, size_t ws_size,
                              hipStream_t stream) {
  const float* x  = (const float*)d_in[0];
  const float* wq = (const float*)d_in[1];
  const float* wk = (const float*)d_in[2];
  const float* wv = (const float*)d_in[3];
  const float* wp = (const float*)d_in[4];

  const size_t SZ_X = (size_t)GM * GN * 2;
  const size_t SZ_W = (size_t)GK * GN * 2;
  char* ws = (char*)d_ws;
  u16* xbf  = (u16*)(ws);
  u16* wqb  = (u16*)(ws + SZ_X);
  u16* wkb  = (u16*)(ws + SZ_X + SZ_W);
  u16* wvb  = (u16*)(ws + SZ_X + 2 * SZ_W);
  u16* wpb  = (u16*)(ws + SZ_X + 3 * SZ_W);
  u16* Qb   = (u16*)(ws + SZ_X + 4 * SZ_W);
  u16* Kb   = (u16*)(ws + 2 * SZ_X + 4 * SZ_W);
  u16* Vb   = (u16*)(ws + 3 * SZ_X + 4 * SZ_W);
  u16* VT   = (u16*)(ws + 4 * SZ_X + 4 * SZ_W);
  u16* X2   = (u16*)(ws + 5 * SZ_X + 4 * SZ_W);
  if (ws_size < 6 * SZ_X + 4 * SZ_W) return;

  cvt_bf16<<<dim3(3072), dim3(256), 0, stream>>>(x, xbf, GM * GN / 4);
  cvt_w4<<<dim3(576, 4), dim3(256), 0, stream>>>(wq, wk, wv, wp, wqb, wkb, wvb, wpb, GK * GN / 4);

  gemm_qkv<<<dim3(32, 6, 3), dim3(256), 0, stream>>>(xbf, wqb, wkb, wvb, Qb, Kb, Vb);
  vtrans<<<dim3(32, 24), dim3(256), 0, stream>>>(Vb, VT);
  attn<<<dim3(768), dim3(256), 0, stream>>>(Qb, Kb, VT, X2);
  gemm_pool<<<dim3(32, 6), dim3(256), 0, stream>>>(X2, wpb, (float*)d_out);
}

// Round 11
// 105.337 us; speedup vs baseline: 1.5240x; 1.5240x over previous
//
#include <hip/hip_runtime.h>

typedef unsigned short u16;
typedef unsigned int u32;
typedef __attribute__((ext_vector_type(8))) short bf16x8;
typedef __attribute__((ext_vector_type(4))) short bf16x4;
typedef __attribute__((ext_vector_type(4))) float f32x4;
typedef __attribute__((ext_vector_type(4))) unsigned short u16x4;
typedef __attribute__((ext_vector_type(2))) unsigned int u32x2;

// B=2, T=2048, E=768, H=12, HD=64
#define GM 4096   // B*T
#define GN 768
#define GK 768
#define QSCALE 0.18033688011112042f   // 0.125 * log2(e), folded into Q

#define HAS_MFMA16 __has_builtin(__builtin_amdgcn_mfma_f32_16x16x16bf16_1k)

static __device__ __forceinline__ u16 f2bf(float f) {
  union { float f; unsigned u; } v; v.f = f;
  unsigned u = v.u;
  return (u16)((u + 0x7FFFu + ((u >> 16) & 1u)) >> 16);
}

static __device__ __forceinline__ float exp2_hw(float x) {
  float r;
  asm("v_exp_f32 %0, %1" : "=v"(r) : "v"(x));
  return r;
}

// pack two floats to bf16 pair (round-half-up), low half = lo
static __device__ __forceinline__ u32 pack_rn(float lo, float hi) {
  u32 a = __float_as_uint(lo) + 0x8000u;
  u32 b = __float_as_uint(hi) + 0x8000u;
  return (a >> 16) | (b & 0xFFFF0000u);
}

static __device__ __forceinline__ void gld16(const void* g, void* l) {
  __builtin_amdgcn_global_load_lds((__attribute__((address_space(1))) void*)(g),
                                   (__attribute__((address_space(3))) void*)(l),
                                   16, 0, 0);
}

// ---------------- fp32 -> bf16 converts ----------------
__global__ void cvt_bf16(const float* __restrict__ in, u16* __restrict__ out, int n4) {
  int i = blockIdx.x * blockDim.x + threadIdx.x;
  if (i < n4) {
    float4 v = ((const float4*)in)[i];
    u16x4 o;
    o[0] = f2bf(v.x); o[1] = f2bf(v.y); o[2] = f2bf(v.z); o[3] = f2bf(v.w);
    ((u16x4*)out)[i] = o;
  }
}

__global__ void cvt_w4(const float* __restrict__ w0, const float* __restrict__ w1,
                       const float* __restrict__ w2, const float* __restrict__ w3,
                       u16* __restrict__ o0, u16* __restrict__ o1,
                       u16* __restrict__ o2, u16* __restrict__ o3, int n4) {
  const float* in = blockIdx.y == 0 ? w0 : (blockIdx.y == 1 ? w1 : (blockIdx.y == 2 ? w2 : w3));
  u16* out = blockIdx.y == 0 ? o0 : (blockIdx.y == 1 ? o1 : (blockIdx.y == 2 ? o2 : o3));
  int i = blockIdx.x * blockDim.x + threadIdx.x;
  if (i < n4) {
    float4 v = ((const float4*)in)[i];
    u16x4 o;
    o[0] = f2bf(v.x); o[1] = f2bf(v.y); o[2] = f2bf(v.z); o[3] = f2bf(v.w);
    ((u16x4*)out)[i] = o;
  }
}

// ---------------- GEMM: C(MxN) = scale * A(MxK) * Bt(NxK)^T ----------------
template<int F32OUT>
static __device__ __forceinline__ void gemm_core(const u16* __restrict__ A,
                                                 const u16* __restrict__ B,
                                                 void* __restrict__ O,
                                                 u16* lA, u16* lB, float scale)
{
  const int tid = threadIdx.x;
  const int wave = tid >> 6, lane = tid & 63;
  const int g = lane >> 4, c = lane & 15;
  const int wr = (wave >> 1) * 64, wc = (wave & 1) * 64;
  const int tm = blockIdx.x * 128, tn = blockIdx.y * 128;

  f32x4 acc[4][4] = {};

  const int srow = lane >> 2;
  const int scolb = (lane & 3) * 16;
  const char* gA = (const char*)(A + (size_t)tm * GK);
  const char* gB = (const char*)(B + (size_t)tn * GK);

  for (int k0 = 0; k0 < GK; k0 += 32) {
#pragma unroll
    for (int i = 0; i < 2; ++i) {
      const int chunk = wave * 2 + i;
      const int row = chunk * 16 + srow;
      gld16(gA + (size_t)row * (GK * 2) + k0 * 2 + scolb, (char*)lA + chunk * 1024);
      gld16(gB + (size_t)row * (GK * 2) + k0 * 2 + scolb, (char*)lB + chunk * 1024);
    }
    __syncthreads();
    bf16x8 af[4], bfr[4];
#pragma unroll
    for (int m = 0; m < 4; ++m)
      af[m] = *(const bf16x8*)((const char*)lA + (wr + m * 16 + c) * 64 + g * 16);
#pragma unroll
    for (int n = 0; n < 4; ++n)
      bfr[n] = *(const bf16x8*)((const char*)lB + (wc + n * 16 + c) * 64 + g * 16);
#pragma unroll
    for (int m = 0; m < 4; ++m)
#pragma unroll
      for (int n = 0; n < 4; ++n)
        acc[m][n] = __builtin_amdgcn_mfma_f32_16x16x32_bf16(af[m], bfr[n], acc[m][n], 0, 0, 0);
    __syncthreads();
  }

#pragma unroll
  for (int m = 0; m < 4; ++m)
#pragma unroll
    for (int n = 0; n < 4; ++n) {
      const int row0 = tm + wr + m * 16 + g * 4;
      const int col = tn + wc + n * 16 + c;
#pragma unroll
      for (int r = 0; r < 4; ++r) {
        if (F32OUT)
          ((float*)O)[(size_t)(row0 + r) * GN + col] = acc[m][n][r];
        else
          ((u16*)O)[(size_t)(row0 + r) * GN + col] = f2bf(acc[m][n][r] * scale);
      }
    }
}

__global__ __launch_bounds__(256) void gemm_qkv(const u16* __restrict__ A,
    const u16* __restrict__ B0, const u16* __restrict__ B1, const u16* __restrict__ B2,
    u16* __restrict__ O0, u16* __restrict__ O1, u16* __restrict__ O2)
{
  __shared__ u16 lA[4096], lB[4096];
  const u16* B = blockIdx.z == 0 ? B0 : (blockIdx.z == 1 ? B1 : B2);
  u16* O = blockIdx.z == 0 ? O0 : (blockIdx.z == 1 ? O1 : O2);
  const float scale = blockIdx.z == 0 ? QSCALE : 1.0f;
  gemm_core<0>(A, B, O, lA, lB, scale);
}

__global__ __launch_bounds__(256) void gemm_pool(const u16* __restrict__ A,
    const u16* __restrict__ B, float* __restrict__ O)
{
  __shared__ u16 lA[4096], lB[4096];
  gemm_core<1>(A, B, O, lA, lB, 1.0f);
}

// ---------------- V transpose: per head (2048x64) -> (64x2048) ----------------
__global__ __launch_bounds__(256) void vtrans(const u16* __restrict__ V, u16* __restrict__ VT) {
  const int tblk = blockIdx.x;
  const int bh = blockIdx.y;
  __shared__ u16 tile[64][72];
  const u16* Vh = V + (size_t)bh * 131072;
  u16* Vt = VT + (size_t)bh * 131072;
  const int tid = threadIdx.x;
  const int t0 = tblk * 64;
#pragma unroll
  for (int i = 0; i < 4; ++i) {
    int idx = i * 256 + tid;
    int row = idx >> 4;
    int c4 = idx & 15;
    u16x4 v = *(const u16x4*)(Vh + (size_t)(t0 + row) * 64 + c4 * 4);
    tile[row][c4 * 4 + 0] = v[0]; tile[row][c4 * 4 + 1] = v[1];
    tile[row][c4 * 4 + 2] = v[2]; tile[row][c4 * 4 + 3] = v[3];
  }
  __syncthreads();
#pragma unroll
  for (int i = 0; i < 4; ++i) {
    int idx = i * 256 + tid;
    int d = idx >> 4;
    int t4 = idx & 15;
    u16x4 o;
    o[0] = tile[t4 * 4 + 0][d]; o[1] = tile[t4 * 4 + 1][d];
    o[2] = tile[t4 * 4 + 2][d]; o[3] = tile[t4 * 4 + 3][d];
    *(u16x4*)(Vt + (size_t)d * 2048 + t0 + t4 * 4) = o;
  }
}

// ---------------- flash attention: R6 structure + register-resident P ----------------
// K,V dbuf-staged in LDS (R6, proven). Swapped QK puts P[key=n*16+g*4+r][qrow=c] in
// lanes — exactly the A-fragment of mfma_f32_16x16x16_bf16 (k=g*4..+3), so PV runs
// as 16 x16-MFMAs with P straight from registers: the P->LDS->P roundtrip (6 LDS
// ops/wave-tile + 8KB LDS) is deleted. Fallback (no builtin): exact R6 path.
static __device__ __forceinline__ void stage_tile(const char* gbase, int rowstride,
                                                  char* lbuf, int wave, int lane) {
#pragma unroll
  for (int i = 0; i < 2; ++i) {
    const int chunk = i * 256 + wave * 64 + lane;
    const int row = chunk >> 3;
    const int colb = (chunk & 7) << 4;
    const char* src = gbase + (size_t)row * rowstride + (colb ^ ((row & 7) << 4));
    char* dst = lbuf + i * 4096 + wave * 1024;
    gld16(src, dst);
  }
}

__global__ __launch_bounds__(256) void attn(const u16* __restrict__ Q,
                                            const u16* __restrict__ Km,
                                            const u16* __restrict__ VT,
                                            u16* __restrict__ X2)
{
  const int qblk = blockIdx.x;
  const int bh = blockIdx.y;
  const int b = bh / 12, h = bh % 12;
  const int tid = threadIdx.x, wave = tid >> 6, lane = tid & 63;
  const int g = lane >> 4, c = lane & 15;
  const int swr = (c & 7) << 4;                   // K/V tile read swizzle (row = *16+c)
  const int swz = ((c & 7) ^ (c >> 3)) << 4;      // P tile swizzle (fallback only)

  __shared__ char Kl[2][8192];
  __shared__ char Vl[2][8192];
#if !HAS_MFMA16
  __shared__ u16 Plds[4][1024];
  u16* pl = Plds[wave];
#endif
  (void)swz;

  const char* Khb = (const char*)(Km + (size_t)bh * 131072);
  const char* Vhb = (const char*)(VT + (size_t)bh * 131072);   // [64][2048] u16
  const u16* Qh = Q + (size_t)bh * 131072;

  const int q0 = qblk * 64 + wave * 16;
  const int nkt = qblk + 1;

  stage_tile(Khb, 128, Kl[0], wave, lane);
  stage_tile(Vhb, 4096, Vl[0], wave, lane);

  bf16x8 qf[2];
#pragma unroll
  for (int kk = 0; kk < 2; ++kk)
    qf[kk] = *(const bf16x8*)(Qh + (size_t)(q0 + c) * 64 + kk * 32 + g * 8);

  f32x4 oacc[4] = {};
  float lsum = 0.f;

  __syncthreads();   // tile 0 staged (vmcnt drained before barrier)

  for (int kt = 0; kt < nkt; ++kt) {
    const int cur = kt & 1;
    if (kt + 1 < nkt) {
      stage_tile(Khb + (size_t)(kt + 1) * 8192, 128, Kl[cur ^ 1], wave, lane);
      stage_tile(Vhb + (size_t)(kt + 1) * 128, 4096, Vl[cur ^ 1], wave, lane);
    }
    // S^T = K Q^T : D[key][qrow]  (key = n*16 + g*4 + r lane-local, qrow = c)
    f32x4 s[4] = {};
    __builtin_amdgcn_s_setprio(1);
#pragma unroll
    for (int kk = 0; kk < 2; ++kk)
#pragma unroll
      for (int n = 0; n < 4; ++n) {
        bf16x8 kf = *(const bf16x8*)(Kl[cur] + (size_t)(n * 16 + c) * 128 + ((kk * 64 + g * 16) ^ swr));
        s[n] = __builtin_amdgcn_mfma_f32_16x16x32_bf16(kf, qf[kk], s[n], 0, 0, 0);
      }
    __builtin_amdgcn_s_setprio(0);

#if HAS_MFMA16
    // p = 2^s -> bf16x4 A-fragments, entirely in registers
    bf16x4 pa[4];
    if (kt == nkt - 1) {
      const int qrow = q0 + c;
#pragma unroll
      for (int n = 0; n < 4; ++n) {
        const int k0i = kt * 64 + n * 16 + g * 4;
        float p0 = (k0i + 0 > qrow) ? 0.f : exp2_hw(s[n][0]);
        float p1 = (k0i + 1 > qrow) ? 0.f : exp2_hw(s[n][1]);
        float p2 = (k0i + 2 > qrow) ? 0.f : exp2_hw(s[n][2]);
        float p3 = (k0i + 3 > qrow) ? 0.f : exp2_hw(s[n][3]);
        lsum += (p0 + p1) + (p2 + p3);
        u32x2 pw; pw[0] = pack_rn(p0, p1); pw[1] = pack_rn(p2, p3);
        pa[n] = __builtin_bit_cast(bf16x4, pw);
      }
    } else {
#pragma unroll
      for (int n = 0; n < 4; ++n) {
        float p0 = exp2_hw(s[n][0]);
        float p1 = exp2_hw(s[n][1]);
        float p2 = exp2_hw(s[n][2]);
        float p3 = exp2_hw(s[n][3]);
        lsum += (p0 + p1) + (p2 + p3);
        u32x2 pw; pw[0] = pack_rn(p0, p1); pw[1] = pack_rn(p2, p3);
        pa[n] = __builtin_bit_cast(bf16x4, pw);
      }
    }
    // O += P V : 16 x 16x16x16 MFMA, V B-fragments (b64) from staged LDS tile
    __builtin_amdgcn_s_setprio(1);
#pragma unroll
    for (int n = 0; n < 4; ++n)
#pragma unroll
      for (int nn = 0; nn < 4; ++nn) {
        bf16x4 vb = *(const bf16x4*)(Vl[cur] + (size_t)(nn * 16 + c) * 128 + ((n * 32 + g * 8) ^ swr));
        oacc[nn] = __builtin_amdgcn_mfma_f32_16x16x16bf16_1k(pa[n], vb, oacc[nn], 0, 0, 0);
      }
    __builtin_amdgcn_s_setprio(0);
#else
    // fallback: R6 P-LDS path
    if (kt == nkt - 1) {
      const int qrow = q0 + c;
#pragma unroll
      for (int n = 0; n < 4; ++n) {
        const int k0i = kt * 64 + n * 16 + g * 4;
        float p0 = (k0i + 0 > qrow) ? 0.f : exp2_hw(s[n][0]);
        float p1 = (k0i + 1 > qrow) ? 0.f : exp2_hw(s[n][1]);
        float p2 = (k0i + 2 > qrow) ? 0.f : exp2_hw(s[n][2]);
        float p3 = (k0i + 3 > qrow) ? 0.f : exp2_hw(s[n][3]);
        lsum += (p0 + p1) + (p2 + p3);
        u32x2 pw; pw[0] = pack_rn(p0, p1); pw[1] = pack_rn(p2, p3);
        *(u32x2*)((char*)pl + c * 128 + ((n * 32 + g * 8) ^ swz)) = pw;
      }
    } else {
#pragma unroll
      for (int n = 0; n < 4; ++n) {
        float p0 = exp2_hw(s[n][0]);
        float p1 = exp2_hw(s[n][1]);
        float p2 = exp2_hw(s[n][2]);
        float p3 = exp2_hw(s[n][3]);
        lsum += (p0 + p1) + (p2 + p3);
        u32x2 pw; pw[0] = pack_rn(p0, p1); pw[1] = pack_rn(p2, p3);
        *(u32x2*)((char*)pl + c * 128 + ((n * 32 + g * 8) ^ swz)) = pw;
      }
    }
    __builtin_amdgcn_s_setprio(1);
#pragma unroll
    for (int kk = 0; kk < 2; ++kk) {
      bf16x8 pab = *(const bf16x8*)((const char*)pl + c * 128 + ((kk * 64 + g * 16) ^ swz));
#pragma unroll
      for (int n = 0; n < 4; ++n) {
        bf16x8 vfb = *(const bf16x8*)(Vl[cur] + (size_t)(n * 16 + c) * 128 + ((kk * 64 + g * 16) ^ swr));
        oacc[n] = __builtin_amdgcn_mfma_f32_16x16x32_bf16(pab, vfb, oacc[n], 0, 0, 0);
      }
    }
    __builtin_amdgcn_s_setprio(0);
#endif
    __syncthreads();
  }

  // epilogue: reduce lsum across the 4 lanes sharing qrow c, broadcast, normalize
  float tot = lsum;
  tot += __shfl_xor(tot, 16);
  tot += __shfl_xor(tot, 32);
  float linv[4];
#pragma unroll
  for (int r = 0; r < 4; ++r)
    linv[r] = __frcp_rn(__shfl(tot, g * 4 + r));
#pragma unroll
  for (int n = 0; n < 4; ++n)
#pragma unroll
    for (int r = 0; r < 4; ++r) {
      const float o = oacc[n][r] * linv[r];
      const int t = q0 + g * 4 + r;
      X2[((size_t)b * 2048 + t) * 768 + h * 64 + n * 16 + c] = f2bf(o);
    }
}

// ---------------- host ----------------
extern "C" void kernel_launch(void* const* d_in, const int* in_sizes, int n_in,
                              void* d_out, int out_size, void* d_ws, size_t ws_size,
                              hipStream_t stream) {
  const float* x  = (const float*)d_in[0];
  const float* wq = (const float*)d_in[1];
  const float* wk = (const float*)d_in[2];
  const float* wv = (const float*)d_in[3];
  const float* wp = (const float*)d_in[4];

  const size_t SZ_X = (size_t)GM * GN * 2;
  const size_t SZ_W = (size_t)GK * GN * 2;
  char* ws = (char*)d_ws;
  u16* xbf  = (u16*)(ws);
  u16* wqb  = (u16*)(ws + SZ_X);
  u16* wkb  = (u16*)(ws + SZ_X + SZ_W);
  u16* wvb  = (u16*)(ws + SZ_X + 2 * SZ_W);
  u16* wpb  = (u16*)(ws + SZ_X + 3 * SZ_W);
  u16* Qb   = (u16*)(ws + SZ_X + 4 * SZ_W);
  u16* Kb   = (u16*)(ws + 2 * SZ_X + 4 * SZ_W);
  u16* Vb   = (u16*)(ws + 3 * SZ_X + 4 * SZ_W);
  u16* VT   = (u16*)(ws + 4 * SZ_X + 4 * SZ_W);
  u16* X2   = (u16*)(ws + 5 * SZ_X + 4 * SZ_W);
  if (ws_size < 6 * SZ_X + 4 * SZ_W) return;

  cvt_bf16<<<dim3(3072), dim3(256), 0, stream>>>(x, xbf, GM * GN / 4);
  cvt_w4<<<dim3(576, 4), dim3(256), 0, stream>>>(wq, wk, wv, wp, wqb, wkb, wvb, wpb, GK * GN / 4);

  gemm_qkv<<<dim3(32, 6, 3), dim3(256), 0, stream>>>(xbf, wqb, wkb, wvb, Qb, Kb, Vb);
  vtrans<<<dim3(32, 24), dim3(256), 0, stream>>>(Vb, VT);
  attn<<<dim3(32, 24), dim3(256), 0, stream>>>(Qb, Kb, VT, X2);
  gemm_pool<<<dim3(32, 6), dim3(256), 0, stream>>>(X2, wpb, (float*)d_out);
}